// Round 17
// baseline (150.281 us; speedup 1.0000x reference)
//
#include <hip/hip_runtime.h>
#include <stdint.h>

#define NG 4
#define NK 160
#define GD 128
#define ED 512
#define BB 16
#define TT 4096
#define BK 32
#define WTOK 64                      // tokens per block window
static constexpr size_t ZSZ = (size_t)BB * ED * TT;           // 33554432

typedef float f32x4 __attribute__((ext_vector_type(4)));

// d_out FLOAT32: [0,ZSZ) z_q | [ZSZ] loss | codes after.
// ws (floats): [0,4096) bsum | [4096,4736) sc | [8192, 8192+81920) ct[g][d][k]

// ---------------- prep: transpose codebook to [g][d][k] + codeword norms ---
__global__ void prep_kernel(const float* __restrict__ cb, float* __restrict__ sc,
                            float* __restrict__ ct) {
  int i = blockIdx.x * 256 + threadIdx.x;                 // 81920 total
  int g = i / (GD * NK), r = i % (GD * NK), d = r / NK, k = r % NK;
  ct[i] = cb[((size_t)g * NK + k) * GD + d];
  if (i < NG * NK) {
    const float* c = cb + (size_t)i * GD;
    float s = 0.f;
    for (int dd = 0; dd < GD; ++dd) s = fmaf(c[dd], c[dd], s);
    sc[i] = s;
  }
}

// ---------------- main: 512 thr, 8 waves x 20 codes, 1 tok/lane ------------
// r16 structure halved again: acc[20] + ~40 VGPR stays UNDER the 64-reg
// occupancy step (m69) -> 8 waves/SIMD, double r16's TLP. Codes stay on the
// scalar pipe (readfirstlane -> s_load); x via conflict-free ds_read_b32.
__global__ __launch_bounds__(512) void vq_kernel(const float* __restrict__ xin,
                                                 const float* __restrict__ cb,
                                                 const float* __restrict__ sc,
                                                 const float* __restrict__ ct,
                                                 float* __restrict__ out,
                                                 float* __restrict__ bsum) {
  __shared__ __align__(16) float xs[BK * WTOK];           // 8 KB
  __shared__ int kfS[WTOK];

  const int tid = (int)threadIdx.x;
  const int w = tid >> 6;                                 // wave 0..7
  const int l = tid & 63;                                 // lane
  const int g = (int)(blockIdx.x >> 10);                  // 1024 blocks/group
  const int tb = (int)(blockIdx.x & 1023);
  const int b = tb >> 6;
  const int t0 = (tb & 63) << 6;                          // 64-token window

  const float* xbase = xin + ((size_t)(b * ED + g * GD)) * TT + t0;
  const float* ctg = ct + (size_t)g * GD * NK;
  const int kbase = __builtin_amdgcn_readfirstlane(w) * 20;  // -> s_load path

  float acc[20];
#pragma unroll
  for (int j = 0; j < 20; ++j) acc[j] = 0.f;
  float sxa = 0.f;

  const int sdd = tid >> 4, scol = (tid & 15) << 2;       // staging coords
  for (int s = 0; s < 4; ++s) {                           // 4 K-slices
    __syncthreads();                                      // prev reads done
    // stage xs [BK][64]: 512 f32x4, exactly 1 per thread, coalesced
    *(f32x4*)&xs[sdd * WTOK + scol] =
        *(const f32x4*)(xbase + (size_t)(s * BK + sdd) * TT + scol);
    __syncthreads();

#pragma unroll 4
    for (int dd = 0; dd < BK; ++dd) {
      const float xv = xs[dd * WTOK + l];                 // 2/bank: free
      const float* cw = ctg + (size_t)(s * BK + dd) * NK + kbase;  // uniform
      const f32x4 c0 = *(const f32x4*)&cw[0];
      const f32x4 c1 = *(const f32x4*)&cw[4];
      const f32x4 c2 = *(const f32x4*)&cw[8];
      const f32x4 c3 = *(const f32x4*)&cw[12];
      const f32x4 c4 = *(const f32x4*)&cw[16];
      // sx chain (ascending d, parity with r3-r16; 8x redundant, 5% cost)
      sxa = fmaf(xv, xv, sxa);
      // dot chains (ascending d per code, parity with r3-r16)
#pragma unroll
      for (int e = 0; e < 4; ++e) {
        acc[e] = fmaf(xv, c0[e], acc[e]);
        acc[4 + e] = fmaf(xv, c1[e], acc[4 + e]);
        acc[8 + e] = fmaf(xv, c2[e], acc[8 + e]);
        acc[12 + e] = fmaf(xv, c3[e], acc[12 + e]);
        acc[16 + e] = fmaf(xv, c4[e], acc[16 + e]);
      }
    }
  }

  // ---- per-wave argmin over its 20 codes (ascending k, strict <) ----
  const float* scw = sc + g * NK + kbase;
  float best = 3.4e38f;
  int bik = 0;
#pragma unroll
  for (int j = 0; j < 20; ++j) {
    const float dv = (sxa + scw[j]) - 2.0f * acc[j];      // ref formula order
    if (dv < best) { best = dv; bik = kbase + j; }
  }

  // ---- cross-wave merge (reuse xs) ----
  __syncthreads();                                        // k-loop reads done
  float* bestW = xs;                                      // [8][64]
  int* bikW = (int*)xs + 512;                             // [8][64]
  bestW[w * WTOK + l] = best;
  bikW[w * WTOK + l] = bik;
  __syncthreads();

  if (tid < WTOK) {                                       // token owner = tid (wave 0)
    float bf = bestW[tid];
    int kf = bikW[tid];
#pragma unroll
    for (int ww = 1; ww < 8; ++ww) {                      // ascending k order
      float bw = bestW[ww * WTOK + tid];
      int kw = bikW[ww * WTOK + tid];
      if (bw < bf) { bf = bw; kf = kw; }                  // first-min kept
    }
    kfS[tid] = kf;

    // codes_out[b, g, t0+tid]
    out[ZSZ + 1 + ((size_t)(b * NG + g)) * TT + t0 + tid] = (float)kf;

    // loss partial: tid<64 is exactly wave 0 -> deterministic wave reduce
    float s = bf;
#pragma unroll
    for (int off = 32; off > 0; off >>= 1) s += __shfl_down(s, off, 64);
    if (tid == 0) bsum[blockIdx.x] = s;
  }
  __syncthreads();

  // ---- z_q write split across all 512 threads (16 d-rows each) ----
  {
    const int tok = tid & 63;
    const int oct = tid >> 6;                             // 0..7 -> d-block
    const int kf = kfS[tok];
    const f32x4* cw = (const f32x4*)(cb + ((size_t)g * NK + kf) * GD) + oct * 4;
    float* zbase = out + ((size_t)(b * ED + g * GD) + (size_t)oct * 16) * TT
                   + t0 + tok;
#pragma unroll 4
    for (int d4 = 0; d4 < 4; ++d4) {
      f32x4 v = cw[d4];
      zbase[(size_t)(4 * d4 + 0) * TT] = v[0];
      zbase[(size_t)(4 * d4 + 1) * TT] = v[1];
      zbase[(size_t)(4 * d4 + 2) * TT] = v[2];
      zbase[(size_t)(4 * d4 + 3) * TT] = v[3];
    }
  }
}

// ---------------- loss ----------------
__global__ __launch_bounds__(64) void loss_kernel(const float* __restrict__ bsum,
                                                  float* __restrict__ out) {
  float s = 0.f;
  for (int j = 0; j < 64; ++j) s += bsum[threadIdx.x + 64 * j];
#pragma unroll
  for (int off = 32; off > 0; off >>= 1) s += __shfl_down(s, off, 64);
  if (threadIdx.x == 0) out[ZSZ] = 1.25f * s / (float)ZSZ;
}

extern "C" void kernel_launch(void* const* d_in, const int* in_sizes, int n_in,
                              void* d_out, int out_size, void* d_ws, size_t ws_size,
                              hipStream_t stream) {
  const float* xin = (const float*)d_in[0];
  const float* cb  = (const float*)d_in[1];
  float* out  = (float*)d_out;
  float* bsum = (float*)d_ws;            // 4096
  float* sc   = (float*)d_ws + 4096;     // 640
  float* ct   = (float*)d_ws + 8192;     // 81920

  prep_kernel<<<320, 256, 0, stream>>>(cb, sc, ct);
  vq_kernel<<<4096, 512, 0, stream>>>(xin, cb, sc, ct, out, bsum);
  loss_kernel<<<1, 64, 0, stream>>>(bsum, out);
}

// Round 18
// 133.067 us; speedup vs baseline: 1.1294x; 1.1294x over previous
//
#include <hip/hip_runtime.h>
#include <stdint.h>

#define NG 4
#define NK 160
#define GD 128
#define ED 512
#define BB 16
#define TT 4096
#define BK 32
#define WTOK 128                     // tokens per block window
static constexpr size_t ZSZ = (size_t)BB * ED * TT;           // 33554432

typedef float f32x4 __attribute__((ext_vector_type(4)));
typedef float f32x2 __attribute__((ext_vector_type(2)));

// d_out FLOAT32: [0,ZSZ) z_q | [ZSZ] loss | codes after.
// ws (floats): [0,2048) bsum | [2048,2688) sc | [4096, 4096+81920) ct[g][d][k]

// ---------------- prep: transpose codebook to [g][d][k] + codeword norms ---
__global__ void prep_kernel(const float* __restrict__ cb, float* __restrict__ sc,
                            float* __restrict__ ct) {
  int i = blockIdx.x * 256 + threadIdx.x;                 // 81920 total
  int g = i / (GD * NK), r = i % (GD * NK), d = r / NK, k = r % NK;
  ct[i] = cb[((size_t)g * NK + k) * GD + d];
  if (i < NG * NK) {
    const float* c = cb + (size_t)i * GD;
    float s = 0.f;
    for (int dd = 0; dd < GD; ++dd) s = fmaf(c[dd], c[dd], s);
    sc[i] = s;
  }
}

// ---------------- main: r16 structure + v_pk_fma_f32 packed math -----------
// 512 thr, 8 waves x 20 codes, 2 tok/lane. Codes via s_load (scalar pipe);
// x via barrier-staged LDS. Inner loop now issues PACKED fp32 FMAs
// (__builtin_elementwise_fma on f32x2 -> v_pk_fma_f32): 21 instead of 42
// VALU instructions per dd per wave. Each acc element's fmaf chain over
// ascending dd is bit-identical to r16 -> argmin parity.
__global__ __launch_bounds__(512) void vq_kernel(const float* __restrict__ xin,
                                                 const float* __restrict__ cb,
                                                 const float* __restrict__ sc,
                                                 const float* __restrict__ ct,
                                                 float* __restrict__ out,
                                                 float* __restrict__ bsum) {
  __shared__ __align__(16) float xs[BK * WTOK];           // 16 KB
  __shared__ int kfS[WTOK];
  __shared__ float wred[2];

  const int tid = (int)threadIdx.x;
  const int w = tid >> 6;                                 // wave 0..7
  const int l = tid & 63;                                 // lane
  const int g = (int)(blockIdx.x >> 9);                   // 512 blocks/group
  const int tb = (int)(blockIdx.x & 511);
  const int b = tb >> 5;
  const int t0 = (tb & 31) << 7;                          // 128-token window

  const float* xbase = xin + ((size_t)(b * ED + g * GD)) * TT + t0;
  const float* ctg = ct + (size_t)g * GD * NK;
  const int kbase = __builtin_amdgcn_readfirstlane(w) * 20;  // -> s_load path

  f32x2 acc2[2][10];
#pragma unroll
  for (int i = 0; i < 2; ++i)
#pragma unroll
    for (int p = 0; p < 10; ++p) acc2[i][p] = (f32x2){0.f, 0.f};
  f32x2 sx2 = (f32x2){0.f, 0.f};

  for (int s = 0; s < 4; ++s) {                           // 4 K-slices
    __syncthreads();                                      // prev reads done
    // stage xs [BK][128]: 1024 f32x4, 2 per thread, coalesced along t
#pragma unroll
    for (int i = 0; i < 2; ++i) {
      int q = i * 512 + tid;
      int dd = q >> 5, col = (q & 31) << 2;
      *(f32x4*)&xs[dd * WTOK + col] =
          *(const f32x4*)(xbase + (size_t)(s * BK + dd) * TT + col);
    }
    __syncthreads();

#pragma unroll 4
    for (int dd = 0; dd < BK; ++dd) {
      const f32x2 xv = *(const f32x2*)&xs[dd * WTOK + l * 2];
      const float* cw = ctg + (size_t)(s * BK + dd) * NK + kbase;  // uniform
      const f32x4 c0 = *(const f32x4*)&cw[0];
      const f32x4 c1 = *(const f32x4*)&cw[4];
      const f32x4 c2 = *(const f32x4*)&cw[8];
      const f32x4 c3 = *(const f32x4*)&cw[12];
      const f32x4 c4 = *(const f32x4*)&cw[16];
      // sx chains for both tokens in one packed fma (ascending d, parity)
      sx2 = __builtin_elementwise_fma(xv, xv, sx2);
      // dot chains: 10 packed fma per token (ascending d per acc element)
#pragma unroll
      for (int i = 0; i < 2; ++i) {
        const f32x2 xx = (f32x2){xv[i], xv[i]};
        acc2[i][0] = __builtin_elementwise_fma(xx, (f32x2){c0[0], c0[1]}, acc2[i][0]);
        acc2[i][1] = __builtin_elementwise_fma(xx, (f32x2){c0[2], c0[3]}, acc2[i][1]);
        acc2[i][2] = __builtin_elementwise_fma(xx, (f32x2){c1[0], c1[1]}, acc2[i][2]);
        acc2[i][3] = __builtin_elementwise_fma(xx, (f32x2){c1[2], c1[3]}, acc2[i][3]);
        acc2[i][4] = __builtin_elementwise_fma(xx, (f32x2){c2[0], c2[1]}, acc2[i][4]);
        acc2[i][5] = __builtin_elementwise_fma(xx, (f32x2){c2[2], c2[3]}, acc2[i][5]);
        acc2[i][6] = __builtin_elementwise_fma(xx, (f32x2){c3[0], c3[1]}, acc2[i][6]);
        acc2[i][7] = __builtin_elementwise_fma(xx, (f32x2){c3[2], c3[3]}, acc2[i][7]);
        acc2[i][8] = __builtin_elementwise_fma(xx, (f32x2){c4[0], c4[1]}, acc2[i][8]);
        acc2[i][9] = __builtin_elementwise_fma(xx, (f32x2){c4[2], c4[3]}, acc2[i][9]);
      }
    }
  }

  // ---- per-wave argmin over its 20 codes (ascending k, strict <) ----
  const float* scw = sc + g * NK + kbase;
  const float sxa[2] = {sx2[0], sx2[1]};
  float best[2] = {3.4e38f, 3.4e38f};
  int bik[2] = {0, 0};
#pragma unroll
  for (int j = 0; j < 20; ++j) {
    const float scv = scw[j];
#pragma unroll
    for (int i = 0; i < 2; ++i) {
      const float dv = (sxa[i] + scv) - 2.0f * acc2[i][j >> 1][j & 1];
      if (dv < best[i]) { best[i] = dv; bik[i] = kbase + j; }
    }
  }

  // ---- cross-wave merge (reuse xs) ----
  __syncthreads();                                        // k-loop reads done
  float* bestW = xs;                                      // [8][128]
  int* bikW = (int*)xs + 1024;                            // [8][128]
  *(f32x2*)&bestW[w * WTOK + l * 2] = (f32x2){best[0], best[1]};
  bikW[w * WTOK + l * 2] = bik[0];
  bikW[w * WTOK + l * 2 + 1] = bik[1];
  __syncthreads();

  if (tid < WTOK) {                                       // token owner = tid
    float bf = bestW[tid];
    int kf = bikW[tid];
#pragma unroll
    for (int ww = 1; ww < 8; ++ww) {                      // ascending k order
      float bw = bestW[ww * WTOK + tid];
      int kw = bikW[ww * WTOK + tid];
      if (bw < bf) { bf = bw; kf = kw; }                  // first-min kept
    }
    kfS[tid] = kf;

    // codes_out[b, g, t0+tid]
    out[ZSZ + 1 + ((size_t)(b * NG + g)) * TT + t0 + tid] = (float)kf;

    // loss partial: deterministic wave reduce (waves 0..1 hold tid<128)
    float s = bf;
#pragma unroll
    for (int off = 32; off > 0; off >>= 1) s += __shfl_down(s, off, 64);
    if (l == 0) wred[w] = s;
  }
  __syncthreads();

  // ---- z_q write split across all 512 threads (quarter d-range each) ----
  {
    const int tok = tid & 127;
    const int quarter = tid >> 7;                         // 0..3 -> d-block
    const int kf = kfS[tok];
    const f32x4* cw = (const f32x4*)(cb + ((size_t)g * NK + kf) * GD) + quarter * 8;
    float* zbase = out + ((size_t)(b * ED + g * GD) + (size_t)quarter * 32) * TT
                   + t0 + tok;
#pragma unroll 4
    for (int d4 = 0; d4 < 8; ++d4) {
      f32x4 v = cw[d4];
      zbase[(size_t)(4 * d4 + 0) * TT] = v[0];
      zbase[(size_t)(4 * d4 + 1) * TT] = v[1];
      zbase[(size_t)(4 * d4 + 2) * TT] = v[2];
      zbase[(size_t)(4 * d4 + 3) * TT] = v[3];
    }
  }

  if (tid == 0) bsum[blockIdx.x] = wred[0] + wred[1];
}

// ---------------- loss ----------------
__global__ __launch_bounds__(64) void loss_kernel(const float* __restrict__ bsum,
                                                  float* __restrict__ out) {
  float s = 0.f;
  for (int j = 0; j < 32; ++j) s += bsum[threadIdx.x + 64 * j];
#pragma unroll
  for (int off = 32; off > 0; off >>= 1) s += __shfl_down(s, off, 64);
  if (threadIdx.x == 0) out[ZSZ] = 1.25f * s / (float)ZSZ;
}

extern "C" void kernel_launch(void* const* d_in, const int* in_sizes, int n_in,
                              void* d_out, int out_size, void* d_ws, size_t ws_size,
                              hipStream_t stream) {
  const float* xin = (const float*)d_in[0];
  const float* cb  = (const float*)d_in[1];
  float* out  = (float*)d_out;
  float* bsum = (float*)d_ws;            // 2048
  float* sc   = (float*)d_ws + 2048;     // 640
  float* ct   = (float*)d_ws + 4096;     // 81920

  prep_kernel<<<320, 256, 0, stream>>>(cb, sc, ct);
  vq_kernel<<<2048, 512, 0, stream>>>(xin, cb, sc, ct, out, bsum);
  loss_kernel<<<1, 64, 0, stream>>>(bsum, out);
}